// Round 12
// baseline (461.992 us; speedup 1.0000x reference)
//
#include <hip/hip_runtime.h>

namespace {

constexpr int T = 1024;
constexpr int B = 1024;
constexpr int L = 10;
constexpr int H = 10;
constexpr int NTHREADS = 128;      // 2 waves: wave0 = layers 0-5, wave1 = layers 6-9
constexpr int U = 8;               // timesteps per interval
constexpr int NWIN = T / U;        // 128 windows
constexpr int NINT = NWIN + L - 1; // 137 intervals
constexpr int BH = B * H;
constexpr int ROWP = 12;           // compact row: 10 real floats + 2 pad (48 B)

using v2f = __attribute__((ext_vector_type(2))) float;
using v4f = __attribute__((ext_vector_type(4))) float;

__device__ __forceinline__ v2f v2fma(v2f a, v2f b, v2f c) {
    return __builtin_elementwise_fma(a, b, c);   // v_pk_fma_f32
}
__device__ __forceinline__ void pin2(v2f& v) { asm volatile("" : "+v"(v)); }
__device__ __forceinline__ float rcp_f(float x) { return __builtin_amdgcn_rcpf(x); }
// bare v_exp_f32 (2^x) - weights are pre-scaled by +/-log2e so no mul needed
__device__ __forceinline__ float exp2_f(float x) {
    float r; asm("v_exp_f32 %0, %1" : "=v"(r) : "v"(x)); return r;
}
__device__ __forceinline__ v2f lo2(v4f q) { return __builtin_shufflevector(q, q, 0, 1); }
__device__ __forceinline__ v2f hi2(v4f q) { return __builtin_shufflevector(q, q, 2, 3); }
#define LDS_FENCE asm volatile("" ::: "memory")

__global__
__attribute__((amdgpu_flat_work_group_size(NTHREADS, NTHREADS)))
__attribute__((amdgpu_waves_per_eu(2)))   // cap VGPR at 256; 2 waves/SIMD resident
void lstm_pipeline(const float* __restrict__ x,    // [T,B,H]
                   const float* __restrict__ hp,   // [L,B,H]
                   const float* __restrict__ cp,   // [L,B,H]
                   const float* __restrict__ Wih,  // [L,4H,H]
                   const float* __restrict__ Whh,  // [L,4H,H]
                   const float* __restrict__ bih,  // [L,4H]
                   const float* __restrict__ bhh,  // [L,4H]
                   float* __restrict__ out,        // [T,B,H]
                   float* __restrict__ hn,         // [L,B,H]
                   float* __restrict__ cn)         // [L,B,H]
{
    // [parity][u][row][compact]; row r = input of layer r (r=0: x, r=l+1:
    // layer-l output). 12-float row stride: layer groups hit disjoint banks.
    __shared__ __align__(16) float buf[2][U][L + 1][ROWP];   // 8448 B

    const int tid = threadIdx.x;
    const int wv = tid >> 6;
    const int ln = tid & 63;
    // (l,j) mapping, proven in prior rounds. Dup lanes repeat valid items of
    // the same wave -> identical values/addresses, benign.
    int lidx;
    if (wv == 0) lidx = (ln < 60) ? ln : (ln - 10);              // dup l=5,j=0..3
    else         lidx = (ln < 40) ? (60 + ln) : (90 + (ln - 40) % 10);  // dup l=9
    const int l = lidx / 10;
    const int j = lidx % 10;
    const int b = blockIdx.x;
    const int boff = b * H + j;

    // ---- weights -> registers, k-pair packed, exp2-prescaled per gate ----
    // wi[g][p] = (W[g-row, 2p], W[g-row, 2p+1]) * scale_g.
    // Gate order g = 0:i 1:f 2:g 3:o; scales: i,f,o -> -log2e, g -> -2*log2e.
    const float NL2E = -1.44269504088896340736f;
    v2f wi[4][5], wh[4][5], bias[4];
    {
        const float* WiL = Wih + (size_t)l * 4 * H * H;
        const float* WhL = Whh + (size_t)l * 4 * H * H;
        const int bo = l * 4 * H;
        #pragma unroll
        for (int g = 0; g < 4; ++g) {
            const float s = (g == 2) ? 2.0f * NL2E : NL2E;
            const float* wr = WiL + (size_t)(g * H + j) * H;
            const float* hr = WhL + (size_t)(g * H + j) * H;
            #pragma unroll
            for (int p = 0; p < 5; ++p) {
                wi[g][p][0] = wr[2 * p] * s; wi[g][p][1] = wr[2 * p + 1] * s;
                wh[g][p][0] = hr[2 * p] * s; wh[g][p][1] = hr[2 * p + 1] * s;
            }
            bias[g][0] = (bih[bo + g * H + j] + bhh[bo + g * H + j]) * s;
            bias[g][1] = 0.0f;
        }
    }
    #pragma unroll
    for (int g = 0; g < 4; ++g) {
        #pragma unroll
        for (int p = 0; p < 5; ++p) { pin2(wi[g][p]); pin2(wh[g][p]); }
        pin2(bias[g]);
    }

    float h = hp[(l * B + b) * H + j];
    float c = cp[(l * B + b) * H + j];
    // Seed own-h row for first active interval k=l (P2(l) u=0 reads parity
    // (l-1)&1 == (l+1)&1, row l+1, u=U-1).
    buf[(l + 1) & 1][U - 1][l + 1][j] = h;

    const bool is_st = (lidx < 10);           // wave0 l=0 primaries stage x
    float xcur[U], xnext[U];
    if (is_st) {
        #pragma unroll
        for (int u = 0; u < U; ++u)           // window 0 -> parity 1 (rp of k=0)
            buf[1][u][0][j] = x[(size_t)u * BH + boff];
        #pragma unroll
        for (int u = 0; u < U; ++u) xcur[u] = x[(size_t)(U + u) * BH + boff];
    }
    __syncthreads();

    // x-projection accumulators (per u, per gate); wave1: live across barrier.
    v2f acc[U][4];

    auto prefetchx = [&](int k) {
        if (is_st && (k + 2) < NWIN) {
            #pragma unroll
            for (int u = 0; u < U; ++u)
                xnext[u] = x[(size_t)((k + 2) * U + u) * BH + boff];
        }
    };

    // p1 (UNGUARDED): x-projections for interval k, reading row l parity rp.
    auto p1 = [&](int k, int rp) {
        #pragma unroll
        for (int u = 0; u < U; ++u) {
            const float* xr = &buf[rp][u][l][0];
            v4f q0 = *(const v4f*)(xr + 0);
            v4f q1 = *(const v4f*)(xr + 4);
            v2f q2 = *(const v2f*)(xr + 8);
            #pragma unroll
            for (int g = 0; g < 4; ++g) {
                v2f a = v2fma(wi[g][0], lo2(q0), bias[g]);
                a = v2fma(wi[g][1], hi2(q0), a);
                a = v2fma(wi[g][2], lo2(q1), a);
                a = v2fma(wi[g][3], hi2(q1), a);
                a = v2fma(wi[g][4], q2, a);
                acc[u][g] = a;
            }
        }
    };

    // p2 (UNGUARDED): recurrence for interval k; writes parity wp, h-carry
    // from parity rp. Consumes acc from p1(k). Split 3+2 FMA chains per gate
    // shorten the dependent path; exp2 arg folded off-chain via (s*num)*rd.
    auto p2 = [&](int k, int wp, int rp) {
        const float* hr0 = &buf[rp][U - 1][l + 1][0];
        v4f hq0 = *(const v4f*)(hr0 + 0);
        v4f hq1 = *(const v4f*)(hr0 + 4);
        v2f hq2 = *(const v2f*)(hr0 + 8);
        float hv[U];
        #pragma unroll
        for (int u = 0; u < U; ++u) {
            v4f q0, q1; v2f q2;
            if (u == 0) { q0 = hq0; q1 = hq1; q2 = hq2; }
            else {
                const float* hr = &buf[wp][u - 1][l + 1][0];
                q0 = *(const v4f*)(hr + 0);
                q1 = *(const v4f*)(hr + 4);
                q2 = *(const v2f*)(hr + 8);
            }
            v2f aI1 = v2fma(wh[0][0], lo2(q0), acc[u][0]);
            v2f aF1 = v2fma(wh[1][0], lo2(q0), acc[u][1]);
            v2f aG1 = v2fma(wh[2][0], lo2(q0), acc[u][2]);
            v2f aO1 = v2fma(wh[3][0], lo2(q0), acc[u][3]);
            v2f aI2 = wh[0][1] * hi2(q0);
            v2f aF2 = wh[1][1] * hi2(q0);
            v2f aG2 = wh[2][1] * hi2(q0);
            v2f aO2 = wh[3][1] * hi2(q0);
            aI1 = v2fma(wh[0][2], lo2(q1), aI1);
            aF1 = v2fma(wh[1][2], lo2(q1), aF1);
            aG1 = v2fma(wh[2][2], lo2(q1), aG1);
            aO1 = v2fma(wh[3][2], lo2(q1), aO1);
            aI2 = v2fma(wh[0][3], hi2(q1), aI2);
            aF2 = v2fma(wh[1][3], hi2(q1), aF2);
            aG2 = v2fma(wh[2][3], hi2(q1), aG2);
            aO2 = v2fma(wh[3][3], hi2(q1), aO2);
            aI1 = v2fma(wh[0][4], q2, aI1);
            aF1 = v2fma(wh[1][4], q2, aF1);
            aG1 = v2fma(wh[2][4], q2, aG1);
            aO1 = v2fma(wh[3][4], q2, aO1);
            const v2f aI = aI1 + aI2;
            const v2f aF = aF1 + aF2;
            const v2f aG = aG1 + aG2;
            const v2f aO = aO1 + aO2;
            const float pI = aI[0] + aI[1];   // pre_i * -log2e
            const float pF = aF[0] + aF[1];   // pre_f * -log2e
            const float pG = aG[0] + aG[1];   // pre_g * -2log2e
            const float pO = aO[0] + aO[1];   // pre_o * -log2e
            // 7-trans activation (5 exp2 + 2 rcp), proven R5-R11:
            //   c' = [c*d2 + (1-Eg)*d1] / (d1*d2), d1=1+Ef, d2=(1+Ei)(1+Eg)
            //   h  = (1-Ec) / ((1+Eo)(1+Ec)), Ec = 2^((s*num)*rd)
            const float Ei = exp2_f(pI);
            const float Ef = exp2_f(pF);
            const float Eg = exp2_f(pG);
            const float Eo = exp2_f(pO);
            const float d1 = 1.0f + Ef;
            const float e1 = 1.0f + Ei;
            const float e2 = 1.0f + Eg;
            const float d2 = e1 * e2;
            const float num = fmaf(c, d2, (1.0f - Eg) * d1);
            const float rd = rcp_f(d1 * d2);
            const float nums = (2.0f * NL2E) * num;   // off-chain (|| rcp)
            c = num * rd;
            const float Ec = exp2_f(nums * rd);
            const float o1 = 1.0f + Eo;
            const float o2 = 1.0f + Ec;
            h = (1.0f - Ec) * rcp_f(o1 * o2);
            buf[wp][u][l + 1][j] = h;         // single b32 write; l=9 -> pad row
            hv[u] = h;
        }
        if (l == L - 1) {                     // batched out-stores (dups benign)
            const int t0 = (int)(unsigned)(k - l) * U;
            #pragma unroll
            for (int u = 0; u < U; ++u)
                out[(size_t)(t0 + u) * BH + boff] = hv[u];
        }
    };

    auto stagex = [&](int k, int wp) {
        if (is_st && (k + 1) < NWIN) {
            #pragma unroll
            for (int u = 0; u < U; ++u) buf[wp][u][0][j] = xcur[u];
            #pragma unroll
            for (int u = 0; u < U; ++u) xcur[u] = xnext[u];
        }
    };

    // Anti-aligned schedule (R6/R9). NEW in R12: wave0's p1+p2 share ONE
    // guard and have NO fences between them -- p1 touches only parity rp,
    // p2 only parity wp (disjoint), so the scheduler may interleave freely
    // (p1's 160 independent pk_fma fill p2's chain-stall slots).
    // wave1 keeps the fence: its p1 reads rows 7-9 written by its own p2
    // at the SAME parity (real cross-lane same-wave dep), and runs its
    // serial p2 at raised priority (role-diverse waves -> setprio pays).
    if (wv == 0) {
        for (int kk = 0; kk < NINT + 1; kk += 2) {   // literal parities
            prefetchx(kk);
            if ((unsigned)(kk - l) < (unsigned)NWIN) { p1(kk, 1); p2(kk, 0, 1); }
            stagex(kk, 0);
            __syncthreads();
            prefetchx(kk + 1);
            if ((unsigned)(kk + 1 - l) < (unsigned)NWIN) { p1(kk + 1, 0); p2(kk + 1, 1, 0); }
            stagex(kk + 1, 1);
            __syncthreads();
        }
    } else {
        for (int kk = 0; kk < NINT + 1; kk += 2) {
            __builtin_amdgcn_s_setprio(1);
            if ((unsigned)(kk - 1 - l) < (unsigned)NWIN) p2(kk - 1, 1, 0);
            __builtin_amdgcn_s_setprio(0);
            LDS_FENCE;   // order p2 writes (rows 7-10, par 1) before p1 reads
            if ((unsigned)(kk - l) < (unsigned)NWIN) p1(kk, 1);
            __syncthreads();
            __builtin_amdgcn_s_setprio(1);
            if ((unsigned)(kk - l) < (unsigned)NWIN) p2(kk, 0, 1);
            __builtin_amdgcn_s_setprio(0);
            LDS_FENCE;
            if ((unsigned)(kk + 1 - l) < (unsigned)NWIN) p1(kk + 1, 0);
            __syncthreads();
        }
    }

    hn[(l * B + b) * H + j] = h;   // dup lanes store identical values
    cn[(l * B + b) * H + j] = c;
}

} // namespace

extern "C" void kernel_launch(void* const* d_in, const int* in_sizes, int n_in,
                              void* d_out, int out_size, void* d_ws, size_t ws_size,
                              hipStream_t stream) {
    (void)in_sizes; (void)n_in; (void)d_ws; (void)ws_size; (void)out_size;
    const float* x   = (const float*)d_in[0];
    const float* hp  = (const float*)d_in[1];
    const float* cp  = (const float*)d_in[2];
    const float* Wih = (const float*)d_in[3];
    const float* Whh = (const float*)d_in[4];
    const float* bih = (const float*)d_in[5];
    const float* bhh = (const float*)d_in[6];

    float* out = (float*)d_out;
    float* hn  = out + (size_t)T * B * H;
    float* cn  = hn + (size_t)L * B * H;

    lstm_pipeline<<<dim3(B), dim3(NTHREADS), 0, stream>>>(
        x, hp, cp, Wih, Whh, bih, bhh, out, hn, cn);
}

// Round 13
// 451.895 us; speedup vs baseline: 1.0223x; 1.0223x over previous
//
#include <hip/hip_runtime.h>

namespace {

constexpr int T = 1024;
constexpr int B = 1024;
constexpr int L = 10;
constexpr int H = 10;
constexpr int NTHREADS = 128;      // 2 waves: wave0 = layers 0-5, wave1 = layers 6-9
constexpr int U = 8;               // timesteps per interval
constexpr int NWIN = T / U;        // 128 windows
constexpr int NINT = NWIN + L - 1; // 137 intervals
constexpr int BH = B * H;
constexpr int ROWP = 12;           // compact row: 10 real floats + 2 pad (48 B)

using v2f = __attribute__((ext_vector_type(2))) float;
using v4f = __attribute__((ext_vector_type(4))) float;

__device__ __forceinline__ v2f v2fma(v2f a, v2f b, v2f c) {
    return __builtin_elementwise_fma(a, b, c);   // v_pk_fma_f32
}
__device__ __forceinline__ void pin2(v2f& v) { asm volatile("" : "+v"(v)); }
__device__ __forceinline__ float rcp_f(float x) { return __builtin_amdgcn_rcpf(x); }
// bare v_exp_f32 (2^x) - weights are pre-scaled by +/-log2e so no mul needed
__device__ __forceinline__ float exp2_f(float x) {
    float r; asm("v_exp_f32 %0, %1" : "=v"(r) : "v"(x)); return r;
}
__device__ __forceinline__ v2f lo2(v4f q) { return __builtin_shufflevector(q, q, 0, 1); }
__device__ __forceinline__ v2f hi2(v4f q) { return __builtin_shufflevector(q, q, 2, 3); }
#define LDS_FENCE asm volatile("" ::: "memory")

__global__
__attribute__((amdgpu_flat_work_group_size(NTHREADS, NTHREADS)))
__attribute__((amdgpu_waves_per_eu(2)))   // cap VGPR at 256; 2 waves/SIMD resident
void lstm_pipeline(const float* __restrict__ x,    // [T,B,H]
                   const float* __restrict__ hp,   // [L,B,H]
                   const float* __restrict__ cp,   // [L,B,H]
                   const float* __restrict__ Wih,  // [L,4H,H]
                   const float* __restrict__ Whh,  // [L,4H,H]
                   const float* __restrict__ bih,  // [L,4H]
                   const float* __restrict__ bhh,  // [L,4H]
                   float* __restrict__ out,        // [T,B,H]
                   float* __restrict__ hn,         // [L,B,H]
                   float* __restrict__ cn)         // [L,B,H]
{
    // [parity][u][row][compact]; row r = input of layer r (r=0: x, r=l+1:
    // layer-l output). 12-float row stride: layer groups hit disjoint banks.
    __shared__ __align__(16) float buf[2][U][L + 1][ROWP];   // 8448 B

    const int tid = threadIdx.x;
    const int wv = tid >> 6;
    const int ln = tid & 63;
    // (l,j) mapping, proven in prior rounds. Dup lanes repeat valid items of
    // the same wave -> identical values/addresses, benign.
    int lidx;
    if (wv == 0) lidx = (ln < 60) ? ln : (ln - 10);              // dup l=5,j=0..3
    else         lidx = (ln < 40) ? (60 + ln) : (90 + (ln - 40) % 10);  // dup l=9
    const int l = lidx / 10;
    const int j = lidx % 10;
    const int b = blockIdx.x;
    const int boff = b * H + j;

    // ---- weights -> registers, k-pair packed, exp2-prescaled per gate ----
    // wi[g][p] = (W[g-row, 2p], W[g-row, 2p+1]) * scale_g.
    // Gate order g = 0:i 1:f 2:g 3:o; scales: i,f,o -> -log2e, g -> -2*log2e.
    const float NL2E = -1.44269504088896340736f;
    v2f wi[4][5], wh[4][5], bias[4];
    {
        const float* WiL = Wih + (size_t)l * 4 * H * H;
        const float* WhL = Whh + (size_t)l * 4 * H * H;
        const int bo = l * 4 * H;
        #pragma unroll
        for (int g = 0; g < 4; ++g) {
            const float s = (g == 2) ? 2.0f * NL2E : NL2E;
            const float* wr = WiL + (size_t)(g * H + j) * H;
            const float* hr = WhL + (size_t)(g * H + j) * H;
            #pragma unroll
            for (int p = 0; p < 5; ++p) {
                wi[g][p][0] = wr[2 * p] * s; wi[g][p][1] = wr[2 * p + 1] * s;
                wh[g][p][0] = hr[2 * p] * s; wh[g][p][1] = hr[2 * p + 1] * s;
            }
            bias[g][0] = (bih[bo + g * H + j] + bhh[bo + g * H + j]) * s;
            bias[g][1] = 0.0f;
        }
    }
    #pragma unroll
    for (int g = 0; g < 4; ++g) {
        #pragma unroll
        for (int p = 0; p < 5; ++p) { pin2(wi[g][p]); pin2(wh[g][p]); }
        pin2(bias[g]);
    }

    float h = hp[(l * B + b) * H + j];
    float c = cp[(l * B + b) * H + j];
    // Seed own-h row for first active interval k=l (P2(l) u=0 reads parity
    // (l-1)&1 == (l+1)&1, row l+1, u=U-1).
    buf[(l + 1) & 1][U - 1][l + 1][j] = h;

    const bool is_st = (lidx < 10);           // wave0 l=0 primaries stage x
    float xcur[U], xnext[U];
    if (is_st) {
        #pragma unroll
        for (int u = 0; u < U; ++u)           // window 0 -> parity 1 (rp of k=0)
            buf[1][u][0][j] = x[(size_t)u * BH + boff];
        #pragma unroll
        for (int u = 0; u < U; ++u) xcur[u] = x[(size_t)(U + u) * BH + boff];
    }
    __syncthreads();

    // x-projection accumulators (per u, per gate); wave1: live across barrier.
    v2f acc[U][4];

    auto prefetchx = [&](int k) {
        if (is_st && (k + 2) < NWIN) {
            #pragma unroll
            for (int u = 0; u < U; ++u)
                xnext[u] = x[(size_t)((k + 2) * U + u) * BH + boff];
        }
    };

    // p1 (UNGUARDED): x-projections for interval k, reading row l parity rp.
    auto p1 = [&](int k, int rp) {
        #pragma unroll
        for (int u = 0; u < U; ++u) {
            const float* xr = &buf[rp][u][l][0];
            v4f q0 = *(const v4f*)(xr + 0);
            v4f q1 = *(const v4f*)(xr + 4);
            v2f q2 = *(const v2f*)(xr + 8);
            #pragma unroll
            for (int g = 0; g < 4; ++g) {
                v2f a = v2fma(wi[g][0], lo2(q0), bias[g]);
                a = v2fma(wi[g][1], hi2(q0), a);
                a = v2fma(wi[g][2], lo2(q1), a);
                a = v2fma(wi[g][3], hi2(q1), a);
                a = v2fma(wi[g][4], q2, a);
                acc[u][g] = a;
            }
        }
    };

    // p2 (UNGUARDED): recurrence for interval k; writes parity wp, h-carry
    // from parity rp. Consumes acc from p1(k). Single 5-FMA chains per gate
    // (R11 form): the merged region supplies p1 filler for chain gaps, so
    // minimal instruction count beats a shorter dependent path.
    auto p2 = [&](int k, int wp, int rp) {
        const float* hr0 = &buf[rp][U - 1][l + 1][0];
        v4f hq0 = *(const v4f*)(hr0 + 0);
        v4f hq1 = *(const v4f*)(hr0 + 4);
        v2f hq2 = *(const v2f*)(hr0 + 8);
        float hv[U];
        #pragma unroll
        for (int u = 0; u < U; ++u) {
            v4f q0, q1; v2f q2;
            if (u == 0) { q0 = hq0; q1 = hq1; q2 = hq2; }
            else {
                const float* hr = &buf[wp][u - 1][l + 1][0];
                q0 = *(const v4f*)(hr + 0);
                q1 = *(const v4f*)(hr + 4);
                q2 = *(const v2f*)(hr + 8);
            }
            v2f aI = v2fma(wh[0][0], lo2(q0), acc[u][0]);
            v2f aF = v2fma(wh[1][0], lo2(q0), acc[u][1]);
            v2f aG = v2fma(wh[2][0], lo2(q0), acc[u][2]);
            v2f aO = v2fma(wh[3][0], lo2(q0), acc[u][3]);
            aI = v2fma(wh[0][1], hi2(q0), aI);
            aF = v2fma(wh[1][1], hi2(q0), aF);
            aG = v2fma(wh[2][1], hi2(q0), aG);
            aO = v2fma(wh[3][1], hi2(q0), aO);
            aI = v2fma(wh[0][2], lo2(q1), aI);
            aF = v2fma(wh[1][2], lo2(q1), aF);
            aG = v2fma(wh[2][2], lo2(q1), aG);
            aO = v2fma(wh[3][2], lo2(q1), aO);
            aI = v2fma(wh[0][3], hi2(q1), aI);
            aF = v2fma(wh[1][3], hi2(q1), aF);
            aG = v2fma(wh[2][3], hi2(q1), aG);
            aO = v2fma(wh[3][3], hi2(q1), aO);
            aI = v2fma(wh[0][4], q2, aI);
            aF = v2fma(wh[1][4], q2, aF);
            aG = v2fma(wh[2][4], q2, aG);
            aO = v2fma(wh[3][4], q2, aO);
            const float pI = aI[0] + aI[1];   // pre_i * -log2e
            const float pF = aF[0] + aF[1];   // pre_f * -log2e
            const float pG = aG[0] + aG[1];   // pre_g * -2log2e
            const float pO = aO[0] + aO[1];   // pre_o * -log2e
            // 7-trans activation (5 exp2 + 2 rcp), proven R5-R12:
            //   c' = [c*d2 + (1-Eg)*d1] / (d1*d2), d1=1+Ef, d2=(1+Ei)(1+Eg)
            //   h  = (1-Ec) / ((1+Eo)(1+Ec)), Ec = 2^((s*num)*rd)
            const float Ei = exp2_f(pI);
            const float Ef = exp2_f(pF);
            const float Eg = exp2_f(pG);
            const float Eo = exp2_f(pO);
            const float d1 = 1.0f + Ef;
            const float e1 = 1.0f + Ei;
            const float e2 = 1.0f + Eg;
            const float d2 = e1 * e2;
            const float num = fmaf(c, d2, (1.0f - Eg) * d1);
            const float rd = rcp_f(d1 * d2);
            const float nums = (2.0f * NL2E) * num;   // off-chain (|| rcp)
            c = num * rd;
            const float Ec = exp2_f(nums * rd);
            const float o1 = 1.0f + Eo;
            const float o2 = 1.0f + Ec;
            h = (1.0f - Ec) * rcp_f(o1 * o2);
            buf[wp][u][l + 1][j] = h;         // single b32 write; l=9 -> pad row
            hv[u] = h;
        }
        if (l == L - 1) {                     // batched out-stores (dups benign)
            const int t0 = (int)(unsigned)(k - l) * U;
            #pragma unroll
            for (int u = 0; u < U; ++u)
                out[(size_t)(t0 + u) * BH + boff] = hv[u];
        }
    };

    auto stagex = [&](int k, int wp) {
        if (is_st && (k + 1) < NWIN) {
            #pragma unroll
            for (int u = 0; u < U; ++u) buf[wp][u][0][j] = xcur[u];
            #pragma unroll
            for (int u = 0; u < U; ++u) xcur[u] = xnext[u];
        }
    };

    // Anti-aligned schedule (R6/R9) + merged single-guard region (R12):
    // wave0's p1+p2 share ONE guard and have NO fences between them -- p1
    // touches only parity rp, p2 only parity wp (disjoint), so the scheduler
    // interleaves p1's 160 independent pk_fma into p2's chain-stall slots.
    // wave1 keeps the fence (its p1 reads rows 7-9 written by its own p2 at
    // the SAME parity) and runs its serial p2 at raised priority.
    if (wv == 0) {
        for (int kk = 0; kk < NINT + 1; kk += 2) {   // literal parities
            prefetchx(kk);
            if ((unsigned)(kk - l) < (unsigned)NWIN) { p1(kk, 1); p2(kk, 0, 1); }
            stagex(kk, 0);
            __syncthreads();
            prefetchx(kk + 1);
            if ((unsigned)(kk + 1 - l) < (unsigned)NWIN) { p1(kk + 1, 0); p2(kk + 1, 1, 0); }
            stagex(kk + 1, 1);
            __syncthreads();
        }
    } else {
        for (int kk = 0; kk < NINT + 1; kk += 2) {
            __builtin_amdgcn_s_setprio(1);
            if ((unsigned)(kk - 1 - l) < (unsigned)NWIN) p2(kk - 1, 1, 0);
            __builtin_amdgcn_s_setprio(0);
            LDS_FENCE;   // order p2 writes (rows 7-10, par 1) before p1 reads
            if ((unsigned)(kk - l) < (unsigned)NWIN) p1(kk, 1);
            __syncthreads();
            __builtin_amdgcn_s_setprio(1);
            if ((unsigned)(kk - l) < (unsigned)NWIN) p2(kk, 0, 1);
            __builtin_amdgcn_s_setprio(0);
            LDS_FENCE;
            if ((unsigned)(kk + 1 - l) < (unsigned)NWIN) p1(kk + 1, 0);
            __syncthreads();
        }
    }

    hn[(l * B + b) * H + j] = h;   // dup lanes store identical values
    cn[(l * B + b) * H + j] = c;
}

} // namespace

extern "C" void kernel_launch(void* const* d_in, const int* in_sizes, int n_in,
                              void* d_out, int out_size, void* d_ws, size_t ws_size,
                              hipStream_t stream) {
    (void)in_sizes; (void)n_in; (void)d_ws; (void)ws_size; (void)out_size;
    const float* x   = (const float*)d_in[0];
    const float* hp  = (const float*)d_in[1];
    const float* cp  = (const float*)d_in[2];
    const float* Wih = (const float*)d_in[3];
    const float* Whh = (const float*)d_in[4];
    const float* bih = (const float*)d_in[5];
    const float* bhh = (const float*)d_in[6];

    float* out = (float*)d_out;
    float* hn  = out + (size_t)T * B * H;
    float* cn  = hn + (size_t)L * B * H;

    lstm_pipeline<<<dim3(B), dim3(NTHREADS), 0, stream>>>(
        x, hp, cp, Wih, Whh, bih, bhh, out, hn, cn);
}